// Round 7
// baseline (234.928 us; speedup 1.0000x reference)
//
#include <hip/hip_runtime.h>
#include <hip/hip_bf16.h>
#include <math.h>

#define B_   8
#define T_   2048
#define DIN  1024
#define H_   1024
#define G_   16
#define M_   (B_ * T_)   // 16384
#define NCH  (B_ * H_)   // 8192 channels
#define SUB  32          // timesteps per scan subchunk
#define NSUB (T_ / SUB)  // 64 subchunks per channel

#define LN2f     0.69314718056f
#define LOG2Ef   1.44269504089f

typedef __bf16 bf16_t;
typedef unsigned char u8;
typedef long long i64;
typedef long long i64x2 __attribute__((ext_vector_type(2)));
typedef float  f32x4  __attribute__((ext_vector_type(4)));
typedef float  f32x16 __attribute__((ext_vector_type(16)));
typedef unsigned short u16x2 __attribute__((ext_vector_type(2)));
typedef unsigned short u16x4 __attribute__((ext_vector_type(4)));
typedef unsigned short u16x8 __attribute__((ext_vector_type(8)));

__device__ __forceinline__ float bf2f(unsigned short u) {
    union { unsigned int i; float f; } c; c.i = ((unsigned int)u) << 16; return c.f;
}
__device__ __forceinline__ unsigned short f2bf(float f) {
    union { __bf16 h; unsigned short u; } c; c.h = (__bf16)f; return c.u;
}
__device__ __forceinline__ float fexp2(float x) { return __builtin_amdgcn_exp2f(x); }
__device__ __forceinline__ float flog2(float x) { return __builtin_amdgcn_logf(x); }

__device__ __forceinline__ float log_g_dev(float x) {
    return (x >= 0.f) ? LN2f * flog2(x + 0.5f)
                      : (x - LN2f * flog2(1.f + fexp2(x * LOG2Ef)));
}
__device__ __forceinline__ float logaddexp_f(float a, float b) {
    float m = fmaxf(a, b);
    float d = -fabsf(a - b);                 // <= 0 (or -inf)
    return m + LN2f * flog2(1.f + fexp2(d * LOG2Ef));
}

// async global->LDS, 16 bytes per lane; LDS dest = uniform base + lane*16
__device__ __forceinline__ void async16(void* lds, const void* g) {
    __builtin_amdgcn_global_load_lds(
        (const __attribute__((address_space(1))) void*)g,
        (__attribute__((address_space(3))) void*)lds, 16, 0, 0);
}

// ---------------------------------------------------------------------------
// fp32 -> fp8 e4m3 bulk convert for X, Wz, Wh (8 elems/thread).
// k-interleaved layout: within each 64-byte K-group, orig 8-byte chunk
// c (k = ks*32 + q*8) is stored at chunk c' = q*2 + ks.  Inverse:
// stored chunk c' holds original c = (c'>>1) + (c'&1)*4.  Hence a b128 at
// 16-B slot hi yields original chunks {hi, hi+4} = the (s0,s2) operand pair
// for 32x32x16 MFMA (lane-half hi), and slot 2^hi yields (s1,s3).
// ---------------------------------------------------------------------------
#define NX8 (M_ * DIN / 8)
#define NW8 (H_ * DIN / 8)

__global__ __launch_bounds__(256) void cvt_all(
    const float* __restrict__ x,  u8* __restrict__ Xb,
    const float* __restrict__ wz, u8* __restrict__ Wzb,
    const float* __restrict__ wh, u8* __restrict__ Whb)
{
    int i = blockIdx.x * 256 + threadIdx.x;
    const float* src; u8* dst;
    if (i < NX8)            { src = x;  dst = Xb; }
    else if (i < NX8 + NW8) { src = wz; dst = Wzb; i -= NX8; }
    else                    { src = wh; dst = Whb; i -= NX8 + NW8; }
    float4 a = ((const float4*)src)[2 * i];
    float4 b = ((const float4*)src)[2 * i + 1];
    int lo = __builtin_amdgcn_cvt_pk_fp8_f32(a.x, a.y, 0,  false);
    lo     = __builtin_amdgcn_cvt_pk_fp8_f32(a.z, a.w, lo, true);
    int hi = __builtin_amdgcn_cvt_pk_fp8_f32(b.x, b.y, 0,  false);
    hi     = __builtin_amdgcn_cvt_pk_fp8_f32(b.z, b.w, hi, true);
    int2 o; o.x = lo; o.y = hi;
    const int c  = i & 7;                       // orig chunk in 64B group
    const int cp = ((c & 3) << 1) | (c >> 2);   // interleaved chunk
    ((int2*)dst)[(i & ~7) | cp] = o;
}

// ---------------------------------------------------------------------------
// fp8 MFMA GEMM: 128x64 tile, BK=64 bytes, 16 K-iters (R2's proven pipeline:
// 3-stage LDS, counted s_waitcnt vmcnt(4) + raw s_barrier, swizzled LDS,
// 8x ds_read_b128 per wave-iter).
// NEW: 32x32x16 fp8 MFMA (16 instrs/iter of 32 rows x 32 cols) replacing
// 32x 16x16x32 — same operand bytes, ~18% fewer MFMA-pipe cycles (measured
// 32x32 rate 2382+ TF vs 16x16 2047 TF).  Same 64 acc regs, same LDS, same
// 3 blocks/CU.
// Epilogue: 32x32 C/D layout col=lane&31, row=(reg&3)+8*(reg>>2)+4*(lane>>5).
// ---------------------------------------------------------------------------
#define BM 128
#define BN 64
#define BKB 64          // k bytes per stage
#define STRD 72         // output-transpose stride (elems)
#define STG_Z 8192      // byte offset of Z within stage
#define STG_H 12288     // byte offset of H within stage
#define STG_BYTES 16384 // bytes per stage (A 8K | Z 4K | H 4K)

__global__ __launch_bounds__(256, 3) void gemm_mfma(
    const u8* __restrict__ Xb,
    const u8* __restrict__ Wzb, const float* __restrict__ bz,
    const u8* __restrict__ Whb, const float* __restrict__ bh,
    bf16_t* __restrict__ Cb, bf16_t* __restrict__ Vb,
    float* __restrict__ Nbuf)
{
    __shared__ __align__(16) char smem[50176];      // 3x16KB staging + 1KB sN
    char* sbase = smem;
    unsigned short* sT = (unsigned short*)smem;     // 18 KB, aliases staging
    float* sN = (float*)(smem + 49152);             // [2][BM]

    const int tid  = threadIdx.x;
    const int m0   = blockIdx.x * BM;
    const int n0   = blockIdx.y * BN;
    const int lane = tid & 63;
    const int wave = tid >> 6;
    const int wm = wave & 1, wn = wave >> 1;   // wave tile: rows wm*64, cols wn*32

    // staging: wave stages A subtiles (2w, 2w+1), Z/H subtile w.
    // LDS slot linear; global source chunk q = (l&3)^((r>>1)&3) (involution)
    const int sr = lane >> 2;
    const int sq = (lane & 3) ^ ((sr >> 1) & 3);
    const size_t gA0 = (size_t)(m0 + wave * 32      + sr) * DIN + sq * 16;
    const size_t gA1 = (size_t)(m0 + wave * 32 + 16 + sr) * DIN + sq * 16;
    const size_t gB0 = (size_t)(n0 + wave * 16      + sr) * DIN + sq * 16;
    const int oA0 = (wave * 2    ) * 1024;
    const int oA1 = (wave * 2 + 1) * 1024;
    const int oZ0 = STG_Z + wave * 1024;
    const int oH0 = STG_H + wave * 1024;

    // 32x32x16 fragment addressing: lane = (hi<<5) | (sub32<<4) | fr
    //   A row (B col) within 32-tile = lane&31; k = hi*8 + byte per k-step.
    //   b128 at slot (hi^sw) -> (s0,s2) operands; slot ((2^hi)^sw) -> (s1,s3).
    const int hi    = lane >> 5;
    const int fr    = lane & 15;
    const int sub32 = (lane & 31) >> 4;
    const int sw    = (fr >> 1) & 3;
    const int foA   = fr * 64;
    const int slot02 = ((hi ^ sw) << 4);
    const int slot13 = (((2 ^ hi) ^ sw) << 4);

    f32x16 dz2[2], dh2[2];
    #pragma unroll
    for (int i = 0; i < 2; ++i) { dz2[i] = (f32x16)0.f; dh2[i] = (f32x16)0.f; }

    char* pc = sbase;                   // compute stage
    char* pn = sbase + STG_BYTES;       // next stage (loads in flight)
    char* pi = sbase + 2 * STG_BYTES;   // issue target (2 ahead)

    auto stage = [&](char* p, int koff) {
        async16(p + oA0, Xb  + gA0 + koff);
        async16(p + oA1, Xb  + gA1 + koff);
        async16(p + oZ0, Wzb + gB0 + koff);
        async16(p + oH0, Whb + gB0 + koff);
    };

    // prologue: issue iters 0 and 1 (8 loads outstanding per wave)
    stage(pc, 0);
    stage(pn, BKB);

    const int kIters = DIN / BKB;    // 16
    for (int it = 0; it < kIters; ++it) {
        if (it < kIters - 1) asm volatile("s_waitcnt vmcnt(4)" ::: "memory");
        else                 asm volatile("s_waitcnt vmcnt(0)" ::: "memory");
        __builtin_amdgcn_s_barrier();
        if (it + 2 < kIters) stage(pi, (it + 2) * BKB);

        i64x2 a02[2], a13[2];
        #pragma unroll
        for (int i = 0; i < 2; ++i) {
            const char* ab = pc + (wm * 4 + i * 2 + sub32) * 1024 + foA;
            a02[i] = *(const i64x2*)(ab + slot02);
            a13[i] = *(const i64x2*)(ab + slot13);
        }
        const char* zb = pc + STG_Z + (wn * 2 + sub32) * 1024 + foA;
        const char* hb = pc + STG_H + (wn * 2 + sub32) * 1024 + foA;
        i64x2 z02 = *(const i64x2*)(zb + slot02);
        i64x2 z13 = *(const i64x2*)(zb + slot13);
        i64x2 h02 = *(const i64x2*)(hb + slot02);
        i64x2 h13 = *(const i64x2*)(hb + slot13);

        #pragma unroll
        for (int i = 0; i < 2; ++i) {
            dz2[i] = __builtin_amdgcn_mfma_f32_32x32x16_fp8_fp8(a02[i].x, z02.x, dz2[i], 0, 0, 0);
            dh2[i] = __builtin_amdgcn_mfma_f32_32x32x16_fp8_fp8(a02[i].x, h02.x, dh2[i], 0, 0, 0);
            dz2[i] = __builtin_amdgcn_mfma_f32_32x32x16_fp8_fp8(a13[i].x, z13.x, dz2[i], 0, 0, 0);
            dh2[i] = __builtin_amdgcn_mfma_f32_32x32x16_fp8_fp8(a13[i].x, h13.x, dh2[i], 0, 0, 0);
            dz2[i] = __builtin_amdgcn_mfma_f32_32x32x16_fp8_fp8(a02[i].y, z02.y, dz2[i], 0, 0, 0);
            dh2[i] = __builtin_amdgcn_mfma_f32_32x32x16_fp8_fp8(a02[i].y, h02.y, dh2[i], 0, 0, 0);
            dz2[i] = __builtin_amdgcn_mfma_f32_32x32x16_fp8_fp8(a13[i].y, z13.y, dz2[i], 0, 0, 0);
            dh2[i] = __builtin_amdgcn_mfma_f32_32x32x16_fp8_fp8(a13[i].y, h13.y, dh2[i], 0, 0, 0);
        }
        char* t = pc; pc = pn; pn = pi; pi = t;
    }
    __syncthreads();                 // all LDS reads done; sT may alias staging

    // ---- epilogue. 32x32 D layout: col=lane&31, row=(rg&3)+8*(rg>>2)+4*hi --
    const int cn5  = lane & 31;
    const int colB = wn * 32 + cn5;              // 0..63 in block
    const float bzv = bz[n0 + colB];
    const float bhv = bh[n0 + colB];
    float lc0s[2][16];

    #pragma unroll
    for (int i = 0; i < 2; ++i) {
        #pragma unroll
        for (int rg = 0; rg < 16; ++rg) {
            const int rowB = wm * 64 + i * 32 + (rg & 3) + 8 * (rg >> 2) + 4 * hi;
            float k = dz2[i][rg] + bzv;
            float q = dh2[i][rg] + bhv;
            float t   = LN2f * flog2(1.f + fexp2(-fabsf(k) * LOG2Ef));
            float lz  = fminf(k, 0.f) - t;
            float lc0 = -fmaxf(k, 0.f) - t;
            lc0s[i][rg] = lc0;
            // group-norm partial: sum lc0^2 over this row's 32 cols in-wave
            float v = lc0 * lc0;
            v += __shfl_xor(v, 1);
            v += __shfl_xor(v, 2);
            v += __shfl_xor(v, 4);
            v += __shfl_xor(v, 8);
            v += __shfl_xor(v, 16);
            if (cn5 == 0) sN[wn * BM + rowB] = v;
            sT[rowB * STRD + colB] = f2bf(lz + log_g_dev(q));
        }
    }
    __syncthreads();                 // sT(lv) + sN complete

    // coalesced V store (16B/lane) + Nbuf
    const int trow = tid >> 3;           // 0..31
    const int tc8  = (tid & 7) * 8;      // 0,8,..,56
    #pragma unroll
    for (int p = 0; p < 4; ++p) {
        const int row = p * 32 + trow;
        u16x8 v = *(const u16x8*)&sT[row * STRD + tc8];
        *(u16x8*)((unsigned short*)Vb + (size_t)(m0 + row) * H_ + n0 + tc8) = v;
    }
    if (tid < BM) {
        float nrm = sqrtf(sN[tid] + sN[BM + tid]);
        Nbuf[(size_t)(m0 + tid) * G_ + blockIdx.y] = nrm;
    }
    __syncthreads();                 // sT reads done

    // stage lc0 and store Cb the same way
    #pragma unroll
    for (int i = 0; i < 2; ++i) {
        #pragma unroll
        for (int rg = 0; rg < 16; ++rg) {
            const int rowB = wm * 64 + i * 32 + (rg & 3) + 8 * (rg >> 2) + 4 * hi;
            sT[rowB * STRD + colB] = f2bf(lc0s[i][rg]);
        }
    }
    __syncthreads();
    #pragma unroll
    for (int p = 0; p < 4; ++p) {
        const int row = p * 32 + trow;
        u16x8 v = *(const u16x8*)&sT[row * STRD + tc8];
        *(u16x8*)((unsigned short*)Cb + (size_t)(m0 + row) * H_ + n0 + tc8) = v;
    }
}

// ---------------------------------------------------------------------------
// Shared helper: computes fac[t][g] for rows (b, subg*SUB + t) in LDS.
// ---------------------------------------------------------------------------
__device__ __forceinline__ void block_fac(
    const float* __restrict__ Nbuf, int b, int subg, float (*sFac)[G_])
{
    const int tid = threadIdx.x;
    if (tid < SUB) {
        const size_t row = (size_t)(b * T_ + subg * SUB + tid);
        const float4* np = (const float4*)(Nbuf + row * G_);
        float4 n4[4] = {np[0], np[1], np[2], np[3]};
        float* n = (float*)n4;
        float mx = n[0];
        #pragma unroll
        for (int g = 1; g < G_; ++g) mx = fmaxf(mx, n[g]);
        float se = 0.f;
        #pragma unroll
        for (int g = 0; g < G_; ++g) se += fexp2((n[g] - mx) * LOG2Ef);
        const float lse = mx + LN2f * flog2(se);
        #pragma unroll
        for (int g = 0; g < G_; ++g) sFac[tid][g] = (n[g] - lse) / n[g];
    }
    __syncthreads();
}

// ---------------------------------------------------------------------------
// Phase 1: subchunk summaries. 4 channels/thread, 1024 ch (= one batch)/block,
// grid (B, NSUB) = 512 blocks.
// ---------------------------------------------------------------------------
__global__ __launch_bounds__(256) void scan_sum(
    const bf16_t* __restrict__ Cb, const bf16_t* __restrict__ Vb,
    const float* __restrict__ Nbuf, float2* __restrict__ Sb)
{
    __shared__ float sFac[SUB][G_];
    const int b    = blockIdx.x;
    const int subg = blockIdx.y;
    block_fac(Nbuf, b, subg, sFac);

    const int tid = threadIdx.x;
    const int h0c = tid * 4;                  // 0..1020
    const int g   = tid >> 4;                 // 64 ch per group
    const int ch0 = b * H_ + h0c;

    size_t idx = ((size_t)b * T_ + (size_t)subg * SUB) * H_ + h0c;
    float A[4], Bv[4];
    #pragma unroll
    for (int e = 0; e < 4; ++e) { A[e] = 0.f; Bv[e] = -INFINITY; }

    #pragma unroll 4
    for (int t = 0; t < SUB; ++t) {
        u16x4 c4 = *(const u16x4*)((const unsigned short*)Cb + idx);
        u16x4 v4 = *(const u16x4*)((const unsigned short*)Vb + idx);
        float fac = sFac[t][g];
        #pragma unroll
        for (int e = 0; e < 4; ++e) {
            float c = bf2f(c4[e]) * fac;
            A[e] += c;
            Bv[e] = logaddexp_f(Bv[e] + c, bf2f(v4[e]));
        }
        idx += H_;
    }
    float2* sp = Sb + (size_t)subg * NCH + ch0;
    #pragma unroll
    for (int e = 0; e < 4; ++e) { float2 o; o.x = A[e]; o.y = Bv[e]; sp[e] = o; }
}

// ---------------------------------------------------------------------------
// Phase 1.5: per-channel prefix over subchunk summaries -> Seed[NSUB][NCH].
// ---------------------------------------------------------------------------
__global__ __launch_bounds__(256) void scan_mid(
    const float2* __restrict__ Sb, const float* __restrict__ h0,
    float* __restrict__ Seed)
{
    const int ch = blockIdx.x * 256 + threadIdx.x;   // 0..NCH-1
    float s = log_g_dev(h0[ch]);
    Seed[ch] = s;
    for (int k = 0; k < NSUB - 1; ++k) {
        float2 ab = Sb[(size_t)k * NCH + ch];
        s = logaddexp_f(s + ab.x, ab.y);
        Seed[(size_t)(k + 1) * NCH + ch] = s;
    }
}

// ---------------------------------------------------------------------------
// Phase 2: load seed, 32-step replay + exp output. Grid (B, NSUB).
// ---------------------------------------------------------------------------
__global__ __launch_bounds__(256) void scan_out(
    const bf16_t* __restrict__ Cb, bf16_t* Vb /* == d_out */,
    const float* __restrict__ Nbuf, const float* __restrict__ Seed)
{
    __shared__ float sFac[SUB][G_];
    const int b    = blockIdx.x;
    const int subg = blockIdx.y;
    block_fac(Nbuf, b, subg, sFac);

    const int tid = threadIdx.x;
    const int h0c = tid * 4;
    const int g   = tid >> 4;
    const int ch0 = b * H_ + h0c;

    float4 sv = *(const float4*)(Seed + (size_t)subg * NCH + ch0);
    float s[4] = {sv.x, sv.y, sv.z, sv.w};

    size_t idx = ((size_t)b * T_ + (size_t)subg * SUB) * H_ + h0c;
    #pragma unroll 4
    for (int t = 0; t < SUB; ++t) {
        u16x4 c4 = *(const u16x4*)((const unsigned short*)Cb + idx);
        u16x4 v4 = *(const u16x4*)((const unsigned short*)Vb + idx);
        float fac = sFac[t][g];
        u16x4 o4;
        #pragma unroll
        for (int e = 0; e < 4; ++e) {
            float c = bf2f(c4[e]) * fac;
            s[e] = logaddexp_f(s[e] + c, bf2f(v4[e]));
            o4[e] = f2bf(fexp2(fminf(s[e], 88.f) * LOG2Ef));   // finite
        }
        *(u16x4*)((unsigned short*)Vb + idx) = o4;
        idx += H_;
    }
}

// ---------------------------------------------------------------------------
extern "C" void kernel_launch(void* const* d_in, const int* in_sizes, int n_in,
                              void* d_out, int out_size, void* d_ws, size_t ws_size,
                              hipStream_t stream)
{
    const float* x   = (const float*)d_in[0];
    const float* h0  = (const float*)d_in[1];
    const float* Wz  = (const float*)d_in[2];
    const float* bz  = (const float*)d_in[3];
    const float* Wh  = (const float*)d_in[4];
    const float* bh  = (const float*)d_in[5];

    bf16_t* out = (bf16_t*)d_out;                                 // [B,T,H] bf16
    char*   ws  = (char*)d_ws;
    bf16_t* Cb  = (bf16_t*)ws;                                    // 33.5 MB raw lc0
    float2* Sb  = (float2*)(ws + (size_t)M_ * H_ * 2);            //  4.2 MB (A,B)
    u8*     Xb  = (u8*)((char*)Sb + (size_t)NSUB * NCH * 8);      // 16.8 MB fp8
    u8*     Wzb = Xb + (size_t)M_ * DIN;                          //  1.0 MB fp8
    u8*     Whb = Wzb + (size_t)H_ * DIN;                         //  1.0 MB fp8
    float*  Nb  = (float*)(Whb + (size_t)H_ * DIN);               //  1.0 MB norms
    float*  Seed= Nb + (size_t)M_ * G_;                           //  2.1 MB seeds

    cvt_all<<<NX8 / 256 + 2 * (NW8 / 256), 256, 0, stream>>>(x, Xb, Wz, Wzb, Wh, Whb);
    gemm_mfma<<<dim3(M_ / BM, H_ / BN), 256, 0, stream>>>(Xb, Wzb, bz, Whb, bh, Cb, out, Nb);
    scan_sum<<<dim3(B_, NSUB), 256, 0, stream>>>(Cb, out, Nb, Sb);
    scan_mid<<<NCH / 256, 256, 0, stream>>>(Sb, h0, Seed);
    scan_out<<<dim3(B_, NSUB), 256, 0, stream>>>(Cb, out, Nb, Seed);
}

// Round 8
// 222.096 us; speedup vs baseline: 1.0578x; 1.0578x over previous
//
#include <hip/hip_runtime.h>
#include <hip/hip_bf16.h>
#include <math.h>

#define B_   8
#define T_   2048
#define DIN  1024
#define H_   1024
#define G_   16
#define M_   (B_ * T_)   // 16384
#define NCH  (B_ * H_)   // 8192 channels
#define SUB  32          // timesteps per scan subchunk
#define NSUB (T_ / SUB)  // 64 subchunks per channel

#define LN2f     0.69314718056f
#define LOG2Ef   1.44269504089f

typedef __bf16 bf16_t;
typedef unsigned char u8;
typedef long long i64;
typedef long long i64x2 __attribute__((ext_vector_type(2)));
typedef float  f32x4  __attribute__((ext_vector_type(4)));
typedef unsigned short u16x2 __attribute__((ext_vector_type(2)));
typedef unsigned short u16x4 __attribute__((ext_vector_type(4)));
typedef unsigned short u16x8 __attribute__((ext_vector_type(8)));

__device__ __forceinline__ float bf2f(unsigned short u) {
    union { unsigned int i; float f; } c; c.i = ((unsigned int)u) << 16; return c.f;
}
__device__ __forceinline__ unsigned short f2bf(float f) {
    union { __bf16 h; unsigned short u; } c; c.h = (__bf16)f; return c.u;
}
__device__ __forceinline__ float fexp2(float x) { return __builtin_amdgcn_exp2f(x); }
__device__ __forceinline__ float flog2(float x) { return __builtin_amdgcn_logf(x); }

__device__ __forceinline__ float log_g_dev(float x) {
    return (x >= 0.f) ? LN2f * flog2(x + 0.5f)
                      : (x - LN2f * flog2(1.f + fexp2(x * LOG2Ef)));
}
__device__ __forceinline__ float logaddexp_f(float a, float b) {
    float m = fmaxf(a, b);
    float d = -fabsf(a - b);                 // <= 0 (or -inf)
    return m + LN2f * flog2(1.f + fexp2(d * LOG2Ef));
}

// async global->LDS, 16 bytes per lane; LDS dest = uniform base + lane*16
__device__ __forceinline__ void async16(void* lds, const void* g) {
    __builtin_amdgcn_global_load_lds(
        (const __attribute__((address_space(1))) void*)g,
        (__attribute__((address_space(3))) void*)lds, 16, 0, 0);
}

// ---------------------------------------------------------------------------
// fp32 -> fp8 e4m3 bulk convert for X, Wz, Wh (8 elems/thread).
// k-interleaved layout: within each 64-byte K-group, orig 8-byte chunk
// c (k = ks*32 + q*8, ks=c>>2, q=c&3) is stored at chunk c' = q*2 + ks, so a
// lane's 16 B at byte q*16 hold [k=q*8..+8) | [k=32+q*8..+8)] — both k-steps
// of one MFMA fragment, contiguous (single ds_read_b128/fragment).
// ---------------------------------------------------------------------------
#define NX8 (M_ * DIN / 8)
#define NW8 (H_ * DIN / 8)

__global__ __launch_bounds__(256) void cvt_all(
    const float* __restrict__ x,  u8* __restrict__ Xb,
    const float* __restrict__ wz, u8* __restrict__ Wzb,
    const float* __restrict__ wh, u8* __restrict__ Whb)
{
    int i = blockIdx.x * 256 + threadIdx.x;
    const float* src; u8* dst;
    if (i < NX8)            { src = x;  dst = Xb; }
    else if (i < NX8 + NW8) { src = wz; dst = Wzb; i -= NX8; }
    else                    { src = wh; dst = Whb; i -= NX8 + NW8; }
    float4 a = ((const float4*)src)[2 * i];
    float4 b = ((const float4*)src)[2 * i + 1];
    int lo = __builtin_amdgcn_cvt_pk_fp8_f32(a.x, a.y, 0,  false);
    lo     = __builtin_amdgcn_cvt_pk_fp8_f32(a.z, a.w, lo, true);
    int hi = __builtin_amdgcn_cvt_pk_fp8_f32(b.x, b.y, 0,  false);
    hi     = __builtin_amdgcn_cvt_pk_fp8_f32(b.z, b.w, hi, true);
    int2 o; o.x = lo; o.y = hi;
    const int c  = i & 7;                       // orig chunk in 64B group
    const int cp = ((c & 3) << 1) | (c >> 2);   // interleaved chunk
    ((int2*)dst)[(i & ~7) | cp] = o;
}

// ---------------------------------------------------------------------------
// fp8 MFMA GEMM: 128x64 tile, BK=64 bytes, 16 K-iters — the R2-verified
// structure (62 us, MfmaUtil 44.5, bank-conflict 262K):
//   * 3-stage LDS pipeline, counted s_waitcnt vmcnt(4) + raw s_barrier
//   * conflict-free swizzled LDS staging read as ds_read_b128
//   * 16x16x32 fp8 MFMA (32x32 variant REVERTED: 17x bank conflicts, R7)
// NEW this round:
//   * T1 XCD-aware bijective block swizzle: each XCD gets a contiguous
//     256-block chunk = 2 n-panels (4 MB Wz+Wh = one XCD L2).
//   * merged single-pass epilogue: V and C staged simultaneously into two
//     LDS arrays, 2 barriers instead of 4, no lc0 register carry.
// ---------------------------------------------------------------------------
#define BM 128
#define BN 64
#define BKB 64          // k bytes per stage
#define STRD 72         // output-transpose stride (elems)
#define STG_Z 8192      // byte offset of Z within stage
#define STG_H 12288     // byte offset of H within stage
#define STG_BYTES 16384 // bytes per stage (A 8K | Z 4K | H 4K)

__global__ __launch_bounds__(256, 3) void gemm_mfma(
    const u8* __restrict__ Xb,
    const u8* __restrict__ Wzb, const float* __restrict__ bz,
    const u8* __restrict__ Whb, const float* __restrict__ bh,
    bf16_t* __restrict__ Cb, bf16_t* __restrict__ Vb,
    float* __restrict__ Nbuf)
{
    __shared__ __align__(16) char smem[50176];      // 3x16KB staging + 1KB sN
    char* sbase = smem;
    unsigned short* sTV = (unsigned short*)smem;            // [128][72] = 18432 B
    unsigned short* sTC = (unsigned short*)(smem + 18432);  // [128][72]
    float* sN = (float*)(smem + 49152);                     // [2][BM]

    // ---- T1: XCD-aware bijective remap (2048 blocks, 2048%8==0) ----
    // hw dispatch id (x fastest) round-robins XCDs; give each XCD a
    // contiguous chunk of 256 work-items = 2 full n-panels.
    const int lin = blockIdx.x + blockIdx.y * (M_ / BM);
    const int nl  = (lin & 7) * ((M_ / BM) * (H_ / BN) / 8) + (lin >> 3);
    const int bx  = nl & (M_ / BM - 1);
    const int by  = nl >> 7;                   // / (M_/BM)

    const int tid  = threadIdx.x;
    const int m0   = bx * BM;
    const int n0   = by * BN;
    const int lane = tid & 63;
    const int wave = tid >> 6;
    const int wm = wave & 1, wn = wave >> 1;   // wave tile: rows wm*64, cols wn*32

    // staging: wave stages A m-subtiles (wave*2, wave*2+1), Z/H n-subtile (wave).
    // LDS slot linear; global source chunk q = (l&3)^((r>>1)&3) (involution)
    const int sr = lane >> 2;
    const int sq = (lane & 3) ^ ((sr >> 1) & 3);
    const size_t gA0 = (size_t)(m0 + wave * 32      + sr) * DIN + sq * 16;
    const size_t gA1 = (size_t)(m0 + wave * 32 + 16 + sr) * DIN + sq * 16;
    const size_t gB0 = (size_t)(n0 + wave * 16      + sr) * DIN + sq * 16;
    const int oA0 = (wave * 2    ) * 1024;
    const int oA1 = (wave * 2 + 1) * 1024;
    const int oZ0 = STG_Z + wave * 1024;
    const int oH0 = STG_H + wave * 1024;

    // fragment read: b128 at swizzled slot; first 8B = ks0, second 8B = ks1.
    const int fr = lane & 15;
    const int fq = lane >> 4;
    const int fo = fr * 64 + ((fq ^ ((fr >> 1) & 3)) << 4);

    f32x4 dz[4][2], dh[4][2];
    #pragma unroll
    for (int i = 0; i < 4; ++i)
        #pragma unroll
        for (int j = 0; j < 2; ++j) { dz[i][j] = (f32x4)0.f; dh[i][j] = (f32x4)0.f; }

    char* pc = sbase;                   // compute stage
    char* pn = sbase + STG_BYTES;       // next stage (loads in flight)
    char* pi = sbase + 2 * STG_BYTES;   // issue target (2 ahead)

    auto stage = [&](char* p, int koff) {
        async16(p + oA0, Xb  + gA0 + koff);
        async16(p + oA1, Xb  + gA1 + koff);
        async16(p + oZ0, Wzb + gB0 + koff);
        async16(p + oH0, Whb + gB0 + koff);
    };

    // prologue: issue iters 0 and 1 (8 loads outstanding per wave)
    stage(pc, 0);
    stage(pn, BKB);

    const int kIters = DIN / BKB;    // 16
    for (int it = 0; it < kIters; ++it) {
        if (it < kIters - 1) asm volatile("s_waitcnt vmcnt(4)" ::: "memory");
        else                 asm volatile("s_waitcnt vmcnt(0)" ::: "memory");
        __builtin_amdgcn_s_barrier();
        if (it + 2 < kIters) stage(pi, (it + 2) * BKB);

        i64x2 af[4], bzv[2], bhv[2];
        #pragma unroll
        for (int i = 0; i < 4; ++i)
            af[i] = *(const i64x2*)(pc + (wm * 4 + i) * 1024 + fo);
        #pragma unroll
        for (int j = 0; j < 2; ++j) {
            bzv[j] = *(const i64x2*)(pc + STG_Z + (wn * 2 + j) * 1024 + fo);
            bhv[j] = *(const i64x2*)(pc + STG_H + (wn * 2 + j) * 1024 + fo);
        }
        #pragma unroll
        for (int i = 0; i < 4; ++i)
            #pragma unroll
            for (int j = 0; j < 2; ++j) {
                dz[i][j] = __builtin_amdgcn_mfma_f32_16x16x32_fp8_fp8(af[i].x, bzv[j].x, dz[i][j], 0, 0, 0);
                dh[i][j] = __builtin_amdgcn_mfma_f32_16x16x32_fp8_fp8(af[i].x, bhv[j].x, dh[i][j], 0, 0, 0);
            }
        #pragma unroll
        for (int i = 0; i < 4; ++i)
            #pragma unroll
            for (int j = 0; j < 2; ++j) {
                dz[i][j] = __builtin_amdgcn_mfma_f32_16x16x32_fp8_fp8(af[i].y, bzv[j].y, dz[i][j], 0, 0, 0);
                dh[i][j] = __builtin_amdgcn_mfma_f32_16x16x32_fp8_fp8(af[i].y, bhv[j].y, dh[i][j], 0, 0, 0);
            }
        char* t = pc; pc = pn; pn = pi; pi = t;
    }
    __syncthreads();                 // all LDS reads done; sTV/sTC alias staging

    // ---- merged epilogue. D layout: col = lane&15, row = (lane>>4)*4+reg --
    const int cq = lane >> 4;
    const int cn = lane & 15;
    float ssum[4][4];
    #pragma unroll
    for (int i = 0; i < 4; ++i)
        #pragma unroll
        for (int rr = 0; rr < 4; ++rr) ssum[i][rr] = 0.f;

    #pragma unroll
    for (int j = 0; j < 2; ++j) {
        const int col = wn * 32 + j * 16 + cn;          // 0..63 in block
        const float bzv_ = bz[n0 + col];
        const float bhv_ = bh[n0 + col];
        #pragma unroll
        for (int i = 0; i < 4; ++i) {
            const int lrow = wm * 64 + i * 16 + cq * 4; // 0..127 in block
            #pragma unroll
            for (int rr = 0; rr < 4; ++rr) {
                float k = dz[i][j][rr] + bzv_;
                float q = dh[i][j][rr] + bhv_;
                float t   = LN2f * flog2(1.f + fexp2(-fabsf(k) * LOG2Ef));
                float lz  = fminf(k, 0.f) - t;
                float lc0 = -fmaxf(k, 0.f) - t;
                ssum[i][rr] += lc0 * lc0;
                sTV[(lrow + rr) * STRD + col] = f2bf(lz + log_g_dev(q));
                sTC[(lrow + rr) * STRD + col] = f2bf(lc0);
            }
        }
    }
    // group-norm partial: reduce over the 16 cn-lanes (lane bits 0..3)
    #pragma unroll
    for (int i = 0; i < 4; ++i)
        #pragma unroll
        for (int rr = 0; rr < 4; ++rr) {
            float v = ssum[i][rr];
            v += __shfl_xor(v, 1);
            v += __shfl_xor(v, 2);
            v += __shfl_xor(v, 4);
            v += __shfl_xor(v, 8);
            ssum[i][rr] = v;
        }
    if (cn == 0) {
        #pragma unroll
        for (int i = 0; i < 4; ++i)
            #pragma unroll
            for (int rr = 0; rr < 4; ++rr)
                sN[wn * BM + wm * 64 + i * 16 + cq * 4 + rr] = ssum[i][rr];
    }
    __syncthreads();                 // sTV + sTC + sN complete

    // coalesced stores (16B/lane) + Nbuf
    const int trow = tid >> 3;           // 0..31
    const int tc8  = (tid & 7) * 8;      // 0,8,..,56
    #pragma unroll
    for (int p = 0; p < 4; ++p) {
        const int row = p * 32 + trow;
        u16x8 v = *(const u16x8*)&sTV[row * STRD + tc8];
        *(u16x8*)((unsigned short*)Vb + (size_t)(m0 + row) * H_ + n0 + tc8) = v;
        u16x8 c = *(const u16x8*)&sTC[row * STRD + tc8];
        *(u16x8*)((unsigned short*)Cb + (size_t)(m0 + row) * H_ + n0 + tc8) = c;
    }
    if (tid < BM) {
        float nrm = sqrtf(sN[tid] + sN[BM + tid]);
        Nbuf[(size_t)(m0 + tid) * G_ + by] = nrm;
    }
}

// ---------------------------------------------------------------------------
// Shared helper: computes fac[t][g] for rows (b, subg*SUB + t) in LDS.
// ---------------------------------------------------------------------------
__device__ __forceinline__ void block_fac(
    const float* __restrict__ Nbuf, int b, int subg, float (*sFac)[G_])
{
    const int tid = threadIdx.x;
    if (tid < SUB) {
        const size_t row = (size_t)(b * T_ + subg * SUB + tid);
        const float4* np = (const float4*)(Nbuf + row * G_);
        float4 n4[4] = {np[0], np[1], np[2], np[3]};
        float* n = (float*)n4;
        float mx = n[0];
        #pragma unroll
        for (int g = 1; g < G_; ++g) mx = fmaxf(mx, n[g]);
        float se = 0.f;
        #pragma unroll
        for (int g = 0; g < G_; ++g) se += fexp2((n[g] - mx) * LOG2Ef);
        const float lse = mx + LN2f * flog2(se);
        #pragma unroll
        for (int g = 0; g < G_; ++g) sFac[tid][g] = (n[g] - lse) / n[g];
    }
    __syncthreads();
}

// ---------------------------------------------------------------------------
// Phase 1: subchunk summaries. 4 channels/thread, 1024 ch (= one batch)/block,
// grid (B, NSUB) = 512 blocks.
// ---------------------------------------------------------------------------
__global__ __launch_bounds__(256) void scan_sum(
    const bf16_t* __restrict__ Cb, const bf16_t* __restrict__ Vb,
    const float* __restrict__ Nbuf, float2* __restrict__ Sb)
{
    __shared__ float sFac[SUB][G_];
    const int b    = blockIdx.x;
    const int subg = blockIdx.y;
    block_fac(Nbuf, b, subg, sFac);

    const int tid = threadIdx.x;
    const int h0c = tid * 4;                  // 0..1020
    const int g   = tid >> 4;                 // 64 ch per group
    const int ch0 = b * H_ + h0c;

    size_t idx = ((size_t)b * T_ + (size_t)subg * SUB) * H_ + h0c;
    float A[4], Bv[4];
    #pragma unroll
    for (int e = 0; e < 4; ++e) { A[e] = 0.f; Bv[e] = -INFINITY; }

    #pragma unroll 4
    for (int t = 0; t < SUB; ++t) {
        u16x4 c4 = *(const u16x4*)((const unsigned short*)Cb + idx);
        u16x4 v4 = *(const u16x4*)((const unsigned short*)Vb + idx);
        float fac = sFac[t][g];
        #pragma unroll
        for (int e = 0; e < 4; ++e) {
            float c = bf2f(c4[e]) * fac;
            A[e] += c;
            Bv[e] = logaddexp_f(Bv[e] + c, bf2f(v4[e]));
        }
        idx += H_;
    }
    float2* sp = Sb + (size_t)subg * NCH + ch0;
    #pragma unroll
    for (int e = 0; e < 4; ++e) { float2 o; o.x = A[e]; o.y = Bv[e]; sp[e] = o; }
}

// ---------------------------------------------------------------------------
// Phase 1.5: per-channel prefix over subchunk summaries -> Seed[NSUB][NCH].
// ---------------------------------------------------------------------------
__global__ __launch_bounds__(256) void scan_mid(
    const float2* __restrict__ Sb, const float* __restrict__ h0,
    float* __restrict__ Seed)
{
    const int ch = blockIdx.x * 256 + threadIdx.x;   // 0..NCH-1
    float s = log_g_dev(h0[ch]);
    Seed[ch] = s;
    for (int k = 0; k < NSUB - 1; ++k) {
        float2 ab = Sb[(size_t)k * NCH + ch];
        s = logaddexp_f(s + ab.x, ab.y);
        Seed[(size_t)(k + 1) * NCH + ch] = s;
    }
}

// ---------------------------------------------------------------------------
// Phase 2: load seed, 32-step replay + exp output. Grid (B, NSUB).
// ---------------------------------------------------------------------------
__global__ __launch_bounds__(256) void scan_out(
    const bf16_t* __restrict__ Cb, bf16_t* Vb /* == d_out */,
    const float* __restrict__ Nbuf, const float* __restrict__ Seed)
{
    __shared__ float sFac[SUB][G_];
    const int b    = blockIdx.x;
    const int subg = blockIdx.y;
    block_fac(Nbuf, b, subg, sFac);

    const int tid = threadIdx.x;
    const int h0c = tid * 4;
    const int g   = tid >> 4;
    const int ch0 = b * H_ + h0c;

    float4 sv = *(const float4*)(Seed + (size_t)subg * NCH + ch0);
    float s[4] = {sv.x, sv.y, sv.z, sv.w};

    size_t idx = ((size_t)b * T_ + (size_t)subg * SUB) * H_ + h0c;
    #pragma unroll 4
    for (int t = 0; t < SUB; ++t) {
        u16x4 c4 = *(const u16x4*)((const unsigned short*)Cb + idx);
        u16x4 v4 = *(const u16x4*)((const unsigned short*)Vb + idx);
        float fac = sFac[t][g];
        u16x4 o4;
        #pragma unroll
        for (int e = 0; e < 4; ++e) {
            float c = bf2f(c4[e]) * fac;
            s[e] = logaddexp_f(s[e] + c, bf2f(v4[e]));
            o4[e] = f2bf(fexp2(fminf(s[e], 88.f) * LOG2Ef));   // finite
        }
        *(u16x4*)((unsigned short*)Vb + idx) = o4;
        idx += H_;
    }
}

// ---------------------------------------------------------------------------
extern "C" void kernel_launch(void* const* d_in, const int* in_sizes, int n_in,
                              void* d_out, int out_size, void* d_ws, size_t ws_size,
                              hipStream_t stream)
{
    const float* x   = (const float*)d_in[0];
    const float* h0  = (const float*)d_in[1];
    const float* Wz  = (const float*)d_in[2];
    const float* bz  = (const float*)d_in[3];
    const float* Wh  = (const float*)d_in[4];
    const float* bh  = (const float*)d_in[5];

    bf16_t* out = (bf16_t*)d_out;                                 // [B,T,H] bf16
    char*   ws  = (char*)d_ws;
    bf16_t* Cb  = (bf16_t*)ws;                                    // 33.5 MB raw lc0
    float2* Sb  = (float2*)(ws + (size_t)M_ * H_ * 2);            //  4.2 MB (A,B)
    u8*     Xb  = (u8*)((char*)Sb + (size_t)NSUB * NCH * 8);      // 16.8 MB fp8
    u8*     Wzb = Xb + (size_t)M_ * DIN;                          //  1.0 MB fp8
    u8*     Whb = Wzb + (size_t)H_ * DIN;                         //  1.0 MB fp8
    float*  Nb  = (float*)(Whb + (size_t)H_ * DIN);               //  1.0 MB norms
    float*  Seed= Nb + (size_t)M_ * G_;                           //  2.1 MB seeds

    cvt_all<<<NX8 / 256 + 2 * (NW8 / 256), 256, 0, stream>>>(x, Xb, Wz, Wzb, Wh, Whb);
    gemm_mfma<<<dim3(M_ / BM, H_ / BN), 256, 0, stream>>>(Xb, Wzb, bz, Whb, bh, Cb, out, Nb);
    scan_sum<<<dim3(B_, NSUB), 256, 0, stream>>>(Cb, out, Nb, Sb);
    scan_mid<<<NCH / 256, 256, 0, stream>>>(Sb, h0, Seed);
    scan_out<<<dim3(B_, NSUB), 256, 0, stream>>>(Cb, out, Nb, Seed);
}

// Round 9
// 216.282 us; speedup vs baseline: 1.0862x; 1.0269x over previous
//
#include <hip/hip_runtime.h>
#include <hip/hip_bf16.h>
#include <math.h>

#define B_   8
#define T_   2048
#define DIN  1024
#define H_   1024
#define G_   16
#define M_   (B_ * T_)   // 16384
#define NCH  (B_ * H_)   // 8192 channels
#define SUB  32          // timesteps per scan subchunk
#define NSUB (T_ / SUB)  // 64 subchunks per channel

#define LN2f     0.69314718056f
#define LOG2Ef   1.44269504089f

typedef __bf16 bf16_t;
typedef unsigned char u8;
typedef long long i64;
typedef long long i64x2 __attribute__((ext_vector_type(2)));
typedef float  f32x4  __attribute__((ext_vector_type(4)));
typedef unsigned short u16x2 __attribute__((ext_vector_type(2)));
typedef unsigned short u16x4 __attribute__((ext_vector_type(4)));
typedef unsigned short u16x8 __attribute__((ext_vector_type(8)));

__device__ __forceinline__ float bf2f(unsigned short u) {
    union { unsigned int i; float f; } c; c.i = ((unsigned int)u) << 16; return c.f;
}
__device__ __forceinline__ unsigned short f2bf(float f) {
    union { __bf16 h; unsigned short u; } c; c.h = (__bf16)f; return c.u;
}
__device__ __forceinline__ float fexp2(float x) { return __builtin_amdgcn_exp2f(x); }
__device__ __forceinline__ float flog2(float x) { return __builtin_amdgcn_logf(x); }

__device__ __forceinline__ float log_g_dev(float x) {
    return (x >= 0.f) ? LN2f * flog2(x + 0.5f)
                      : (x - LN2f * flog2(1.f + fexp2(x * LOG2Ef)));
}
__device__ __forceinline__ float logaddexp_f(float a, float b) {
    float m = fmaxf(a, b);
    float d = -fabsf(a - b);                 // <= 0 (or -inf)
    return m + LN2f * flog2(1.f + fexp2(d * LOG2Ef));
}

// async global->LDS, 16 bytes per lane; LDS dest = uniform base + lane*16
__device__ __forceinline__ void async16(void* lds, const void* g) {
    __builtin_amdgcn_global_load_lds(
        (const __attribute__((address_space(1))) void*)g,
        (__attribute__((address_space(3))) void*)lds, 16, 0, 0);
}

// ---------------------------------------------------------------------------
// fp32 -> fp8 e4m3 bulk convert for X, Wz, Wh (8 elems/thread).
// k-interleaved layout: within each 64-byte K-group, orig 8-byte chunk
// c (k = ks*32 + q*8, ks=c>>2, q=c&3) is stored at chunk c' = q*2 + ks, so a
// lane's 16 B at byte q*16 hold [k=q*8..+8) | [k=32+q*8..+8)] — both k-steps
// of one MFMA fragment, contiguous (single ds_read_b128/fragment).
// ---------------------------------------------------------------------------
#define NX8 (M_ * DIN / 8)
#define NW8 (H_ * DIN / 8)

__global__ __launch_bounds__(256) void cvt_all(
    const float* __restrict__ x,  u8* __restrict__ Xb,
    const float* __restrict__ wz, u8* __restrict__ Wzb,
    const float* __restrict__ wh, u8* __restrict__ Whb)
{
    int i = blockIdx.x * 256 + threadIdx.x;
    const float* src; u8* dst;
    if (i < NX8)            { src = x;  dst = Xb; }
    else if (i < NX8 + NW8) { src = wz; dst = Wzb; i -= NX8; }
    else                    { src = wh; dst = Whb; i -= NX8 + NW8; }
    float4 a = ((const float4*)src)[2 * i];
    float4 b = ((const float4*)src)[2 * i + 1];
    int lo = __builtin_amdgcn_cvt_pk_fp8_f32(a.x, a.y, 0,  false);
    lo     = __builtin_amdgcn_cvt_pk_fp8_f32(a.z, a.w, lo, true);
    int hi = __builtin_amdgcn_cvt_pk_fp8_f32(b.x, b.y, 0,  false);
    hi     = __builtin_amdgcn_cvt_pk_fp8_f32(b.z, b.w, hi, true);
    int2 o; o.x = lo; o.y = hi;
    const int c  = i & 7;                       // orig chunk in 64B group
    const int cp = ((c & 3) << 1) | (c >> 2);   // interleaved chunk
    ((int2*)dst)[(i & ~7) | cp] = o;
}

// ---------------------------------------------------------------------------
// fp8 MFMA GEMM: 128x64 tile, BK=64 bytes, 16 K-iters — R2-verified core:
//   * 3-stage LDS pipeline, counted s_waitcnt vmcnt(4) + raw s_barrier
//   * conflict-free swizzled LDS staging read as ds_read_b128
//   * 16x16x32 fp8 MFMA
// XCD swizzle REVERTED (R8: FETCH 27.5->133 MB — default x-fastest mapping
// already gives each XCD a resident A-slice since gridDim.x % 8 == 0).
// KEPT from R8: merged single-pass epilogue (V+C staged simultaneously,
// 2 barriers instead of 4, no lc0 register carry).
// ---------------------------------------------------------------------------
#define BM 128
#define BN 64
#define BKB 64          // k bytes per stage
#define STRD 72         // output-transpose stride (elems)
#define STG_Z 8192      // byte offset of Z within stage
#define STG_H 12288     // byte offset of H within stage
#define STG_BYTES 16384 // bytes per stage (A 8K | Z 4K | H 4K)

__global__ __launch_bounds__(256, 3) void gemm_mfma(
    const u8* __restrict__ Xb,
    const u8* __restrict__ Wzb, const float* __restrict__ bz,
    const u8* __restrict__ Whb, const float* __restrict__ bh,
    bf16_t* __restrict__ Cb, bf16_t* __restrict__ Vb,
    float* __restrict__ Nbuf)
{
    __shared__ __align__(16) char smem[50176];      // 3x16KB staging + 1KB sN
    char* sbase = smem;
    unsigned short* sTV = (unsigned short*)smem;            // [128][72] = 18432 B
    unsigned short* sTC = (unsigned short*)(smem + 18432);  // [128][72]
    float* sN = (float*)(smem + 49152);                     // [2][BM]

    const int tid  = threadIdx.x;
    const int m0   = blockIdx.x * BM;
    const int n0   = blockIdx.y * BN;
    const int lane = tid & 63;
    const int wave = tid >> 6;
    const int wm = wave & 1, wn = wave >> 1;   // wave tile: rows wm*64, cols wn*32

    // staging: wave stages A m-subtiles (wave*2, wave*2+1), Z/H n-subtile (wave).
    // LDS slot linear; global source chunk q = (l&3)^((r>>1)&3) (involution)
    const int sr = lane >> 2;
    const int sq = (lane & 3) ^ ((sr >> 1) & 3);
    const size_t gA0 = (size_t)(m0 + wave * 32      + sr) * DIN + sq * 16;
    const size_t gA1 = (size_t)(m0 + wave * 32 + 16 + sr) * DIN + sq * 16;
    const size_t gB0 = (size_t)(n0 + wave * 16      + sr) * DIN + sq * 16;
    const int oA0 = (wave * 2    ) * 1024;
    const int oA1 = (wave * 2 + 1) * 1024;
    const int oZ0 = STG_Z + wave * 1024;
    const int oH0 = STG_H + wave * 1024;

    // fragment read: b128 at swizzled slot; first 8B = ks0, second 8B = ks1.
    const int fr = lane & 15;
    const int fq = lane >> 4;
    const int fo = fr * 64 + ((fq ^ ((fr >> 1) & 3)) << 4);

    f32x4 dz[4][2], dh[4][2];
    #pragma unroll
    for (int i = 0; i < 4; ++i)
        #pragma unroll
        for (int j = 0; j < 2; ++j) { dz[i][j] = (f32x4)0.f; dh[i][j] = (f32x4)0.f; }

    char* pc = sbase;                   // compute stage
    char* pn = sbase + STG_BYTES;       // next stage (loads in flight)
    char* pi = sbase + 2 * STG_BYTES;   // issue target (2 ahead)

    auto stage = [&](char* p, int koff) {
        async16(p + oA0, Xb  + gA0 + koff);
        async16(p + oA1, Xb  + gA1 + koff);
        async16(p + oZ0, Wzb + gB0 + koff);
        async16(p + oH0, Whb + gB0 + koff);
    };

    // prologue: issue iters 0 and 1 (8 loads outstanding per wave)
    stage(pc, 0);
    stage(pn, BKB);

    const int kIters = DIN / BKB;    // 16
    for (int it = 0; it < kIters; ++it) {
        if (it < kIters - 1) asm volatile("s_waitcnt vmcnt(4)" ::: "memory");
        else                 asm volatile("s_waitcnt vmcnt(0)" ::: "memory");
        __builtin_amdgcn_s_barrier();
        if (it + 2 < kIters) stage(pi, (it + 2) * BKB);

        i64x2 af[4], bzv[2], bhv[2];
        #pragma unroll
        for (int i = 0; i < 4; ++i)
            af[i] = *(const i64x2*)(pc + (wm * 4 + i) * 1024 + fo);
        #pragma unroll
        for (int j = 0; j < 2; ++j) {
            bzv[j] = *(const i64x2*)(pc + STG_Z + (wn * 2 + j) * 1024 + fo);
            bhv[j] = *(const i64x2*)(pc + STG_H + (wn * 2 + j) * 1024 + fo);
        }
        #pragma unroll
        for (int i = 0; i < 4; ++i)
            #pragma unroll
            for (int j = 0; j < 2; ++j) {
                dz[i][j] = __builtin_amdgcn_mfma_f32_16x16x32_fp8_fp8(af[i].x, bzv[j].x, dz[i][j], 0, 0, 0);
                dh[i][j] = __builtin_amdgcn_mfma_f32_16x16x32_fp8_fp8(af[i].x, bhv[j].x, dh[i][j], 0, 0, 0);
            }
        #pragma unroll
        for (int i = 0; i < 4; ++i)
            #pragma unroll
            for (int j = 0; j < 2; ++j) {
                dz[i][j] = __builtin_amdgcn_mfma_f32_16x16x32_fp8_fp8(af[i].y, bzv[j].y, dz[i][j], 0, 0, 0);
                dh[i][j] = __builtin_amdgcn_mfma_f32_16x16x32_fp8_fp8(af[i].y, bhv[j].y, dh[i][j], 0, 0, 0);
            }
        char* t = pc; pc = pn; pn = pi; pi = t;
    }
    __syncthreads();                 // all LDS reads done; sTV/sTC alias staging

    // ---- merged epilogue. D layout: col = lane&15, row = (lane>>4)*4+reg --
    const int cq = lane >> 4;
    const int cn = lane & 15;
    float ssum[4][4];
    #pragma unroll
    for (int i = 0; i < 4; ++i)
        #pragma unroll
        for (int rr = 0; rr < 4; ++rr) ssum[i][rr] = 0.f;

    #pragma unroll
    for (int j = 0; j < 2; ++j) {
        const int col = wn * 32 + j * 16 + cn;          // 0..63 in block
        const float bzv_ = bz[n0 + col];
        const float bhv_ = bh[n0 + col];
        #pragma unroll
        for (int i = 0; i < 4; ++i) {
            const int lrow = wm * 64 + i * 16 + cq * 4; // 0..127 in block
            #pragma unroll
            for (int rr = 0; rr < 4; ++rr) {
                float k = dz[i][j][rr] + bzv_;
                float q = dh[i][j][rr] + bhv_;
                float t   = LN2f * flog2(1.f + fexp2(-fabsf(k) * LOG2Ef));
                float lz  = fminf(k, 0.f) - t;
                float lc0 = -fmaxf(k, 0.f) - t;
                ssum[i][rr] += lc0 * lc0;
                sTV[(lrow + rr) * STRD + col] = f2bf(lz + log_g_dev(q));
                sTC[(lrow + rr) * STRD + col] = f2bf(lc0);
            }
        }
    }
    // group-norm partial: reduce over the 16 cn-lanes (lane bits 0..3)
    #pragma unroll
    for (int i = 0; i < 4; ++i)
        #pragma unroll
        for (int rr = 0; rr < 4; ++rr) {
            float v = ssum[i][rr];
            v += __shfl_xor(v, 1);
            v += __shfl_xor(v, 2);
            v += __shfl_xor(v, 4);
            v += __shfl_xor(v, 8);
            ssum[i][rr] = v;
        }
    if (cn == 0) {
        #pragma unroll
        for (int i = 0; i < 4; ++i)
            #pragma unroll
            for (int rr = 0; rr < 4; ++rr)
                sN[wn * BM + wm * 64 + i * 16 + cq * 4 + rr] = ssum[i][rr];
    }
    __syncthreads();                 // sTV + sTC + sN complete

    // coalesced stores (16B/lane) + Nbuf
    const int trow = tid >> 3;           // 0..31
    const int tc8  = (tid & 7) * 8;      // 0,8,..,56
    #pragma unroll
    for (int p = 0; p < 4; ++p) {
        const int row = p * 32 + trow;
        u16x8 v = *(const u16x8*)&sTV[row * STRD + tc8];
        *(u16x8*)((unsigned short*)Vb + (size_t)(m0 + row) * H_ + n0 + tc8) = v;
        u16x8 c = *(const u16x8*)&sTC[row * STRD + tc8];
        *(u16x8*)((unsigned short*)Cb + (size_t)(m0 + row) * H_ + n0 + tc8) = c;
    }
    if (tid < BM) {
        float nrm = sqrtf(sN[tid] + sN[BM + tid]);
        Nbuf[(size_t)(m0 + tid) * G_ + blockIdx.y] = nrm;
    }
}

// ---------------------------------------------------------------------------
// Shared helper: computes fac[t][g] for rows (b, subg*SUB + t) in LDS.
// ---------------------------------------------------------------------------
__device__ __forceinline__ void block_fac(
    const float* __restrict__ Nbuf, int b, int subg, float (*sFac)[G_])
{
    const int tid = threadIdx.x;
    if (tid < SUB) {
        const size_t row = (size_t)(b * T_ + subg * SUB + tid);
        const float4* np = (const float4*)(Nbuf + row * G_);
        float4 n4[4] = {np[0], np[1], np[2], np[3]};
        float* n = (float*)n4;
        float mx = n[0];
        #pragma unroll
        for (int g = 1; g < G_; ++g) mx = fmaxf(mx, n[g]);
        float se = 0.f;
        #pragma unroll
        for (int g = 0; g < G_; ++g) se += fexp2((n[g] - mx) * LOG2Ef);
        const float lse = mx + LN2f * flog2(se);
        #pragma unroll
        for (int g = 0; g < G_; ++g) sFac[tid][g] = (n[g] - lse) / n[g];
    }
    __syncthreads();
}

// ---------------------------------------------------------------------------
// Phase 1: subchunk summaries. 4 channels/thread, 1024 ch (= one batch)/block,
// grid (B, NSUB) = 512 blocks.
// ---------------------------------------------------------------------------
__global__ __launch_bounds__(256) void scan_sum(
    const bf16_t* __restrict__ Cb, const bf16_t* __restrict__ Vb,
    const float* __restrict__ Nbuf, float2* __restrict__ Sb)
{
    __shared__ float sFac[SUB][G_];
    const int b    = blockIdx.x;
    const int subg = blockIdx.y;
    block_fac(Nbuf, b, subg, sFac);

    const int tid = threadIdx.x;
    const int h0c = tid * 4;                  // 0..1020
    const int g   = tid >> 4;                 // 64 ch per group
    const int ch0 = b * H_ + h0c;

    size_t idx = ((size_t)b * T_ + (size_t)subg * SUB) * H_ + h0c;
    float A[4], Bv[4];
    #pragma unroll
    for (int e = 0; e < 4; ++e) { A[e] = 0.f; Bv[e] = -INFINITY; }

    #pragma unroll 4
    for (int t = 0; t < SUB; ++t) {
        u16x4 c4 = *(const u16x4*)((const unsigned short*)Cb + idx);
        u16x4 v4 = *(const u16x4*)((const unsigned short*)Vb + idx);
        float fac = sFac[t][g];
        #pragma unroll
        for (int e = 0; e < 4; ++e) {
            float c = bf2f(c4[e]) * fac;
            A[e] += c;
            Bv[e] = logaddexp_f(Bv[e] + c, bf2f(v4[e]));
        }
        idx += H_;
    }
    float2* sp = Sb + (size_t)subg * NCH + ch0;
    #pragma unroll
    for (int e = 0; e < 4; ++e) { float2 o; o.x = A[e]; o.y = Bv[e]; sp[e] = o; }
}

// ---------------------------------------------------------------------------
// Phase 1.5: per-channel prefix over subchunk summaries -> Seed[NSUB][NCH].
// ---------------------------------------------------------------------------
__global__ __launch_bounds__(256) void scan_mid(
    const float2* __restrict__ Sb, const float* __restrict__ h0,
    float* __restrict__ Seed)
{
    const int ch = blockIdx.x * 256 + threadIdx.x;   // 0..NCH-1
    float s = log_g_dev(h0[ch]);
    Seed[ch] = s;
    for (int k = 0; k < NSUB - 1; ++k) {
        float2 ab = Sb[(size_t)k * NCH + ch];
        s = logaddexp_f(s + ab.x, ab.y);
        Seed[(size_t)(k + 1) * NCH + ch] = s;
    }
}

// ---------------------------------------------------------------------------
// Phase 2: load seed, 32-step replay + exp output. Grid (B, NSUB).
// ---------------------------------------------------------------------------
__global__ __launch_bounds__(256) void scan_out(
    const bf16_t* __restrict__ Cb, bf16_t* Vb /* == d_out */,
    const float* __restrict__ Nbuf, const float* __restrict__ Seed)
{
    __shared__ float sFac[SUB][G_];
    const int b    = blockIdx.x;
    const int subg = blockIdx.y;
    block_fac(Nbuf, b, subg, sFac);

    const int tid = threadIdx.x;
    const int h0c = tid * 4;
    const int g   = tid >> 4;
    const int ch0 = b * H_ + h0c;

    float4 sv = *(const float4*)(Seed + (size_t)subg * NCH + ch0);
    float s[4] = {sv.x, sv.y, sv.z, sv.w};

    size_t idx = ((size_t)b * T_ + (size_t)subg * SUB) * H_ + h0c;
    #pragma unroll 4
    for (int t = 0; t < SUB; ++t) {
        u16x4 c4 = *(const u16x4*)((const unsigned short*)Cb + idx);
        u16x4 v4 = *(const u16x4*)((const unsigned short*)Vb + idx);
        float fac = sFac[t][g];
        u16x4 o4;
        #pragma unroll
        for (int e = 0; e < 4; ++e) {
            float c = bf2f(c4[e]) * fac;
            s[e] = logaddexp_f(s[e] + c, bf2f(v4[e]));
            o4[e] = f2bf(fexp2(fminf(s[e], 88.f) * LOG2Ef));   // finite
        }
        *(u16x4*)((unsigned short*)Vb + idx) = o4;
        idx += H_;
    }
}

// ---------------------------------------------------------------------------
extern "C" void kernel_launch(void* const* d_in, const int* in_sizes, int n_in,
                              void* d_out, int out_size, void* d_ws, size_t ws_size,
                              hipStream_t stream)
{
    const float* x   = (const float*)d_in[0];
    const float* h0  = (const float*)d_in[1];
    const float* Wz  = (const float*)d_in[2];
    const float* bz  = (const float*)d_in[3];
    const float* Wh  = (const float*)d_in[4];
    const float* bh  = (const float*)d_in[5];

    bf16_t* out = (bf16_t*)d_out;                                 // [B,T,H] bf16
    char*   ws  = (char*)d_ws;
    bf16_t* Cb  = (bf16_t*)ws;                                    // 33.5 MB raw lc0
    float2* Sb  = (float2*)(ws + (size_t)M_ * H_ * 2);            //  4.2 MB (A,B)
    u8*     Xb  = (u8*)((char*)Sb + (size_t)NSUB * NCH * 8);      // 16.8 MB fp8
    u8*     Wzb = Xb + (size_t)M_ * DIN;                          //  1.0 MB fp8
    u8*     Whb = Wzb + (size_t)H_ * DIN;                         //  1.0 MB fp8
    float*  Nb  = (float*)(Whb + (size_t)H_ * DIN);               //  1.0 MB norms
    float*  Seed= Nb + (size_t)M_ * G_;                           //  2.1 MB seeds

    cvt_all<<<NX8 / 256 + 2 * (NW8 / 256), 256, 0, stream>>>(x, Xb, Wz, Wzb, Wh, Whb);
    gemm_mfma<<<dim3(M_ / BM, H_ / BN), 256, 0, stream>>>(Xb, Wzb, bz, Whb, bh, Cb, out, Nb);
    scan_sum<<<dim3(B_, NSUB), 256, 0, stream>>>(Cb, out, Nb, Sb);
    scan_mid<<<NCH / 256, 256, 0, stream>>>(Sb, h0, Seed);
    scan_out<<<dim3(B_, NSUB), 256, 0, stream>>>(Cb, out, Nb, Seed);
}